// Round 1
// baseline (350.393 us; speedup 1.0000x reference)
//
#include <hip/hip_runtime.h>
#include <cstdint>
#include <cstddef>

#define ND    128
#define NK    1024
#define NROWS 8192
#define NB    8        // rows (n) per block in kFactorDist
#define RANK  8
#define LSTRIDE 1028   // 128*8 + 4 pad floats per n  -> conflict-free b128 reads

#define OFF_EMB 8192
#define OFF_CS  139264
#define OFF_EMA 140288

// workspace byte offsets
#define WSB_IDX    0
#define WSB_COUNTS (8192 * 4)
#define WSB_DW     (WSB_COUNTS + 1024 * 4)
#define WSB_NTOT   (WSB_DW + 131072 * 4)

#define ECOMP(v4, c) ((c)==0 ? (v4).x : (c)==1 ? (v4).y : (c)==2 ? (v4).z : (v4).w)

__device__ __forceinline__ void accum_pair(const float* __restrict__ Lrow, int i, int half,
                                           float4 ea, float4 eb,
                                           float* __restrict__ vk0, float* __restrict__ vk1)
{
  const float4 l0 = *(const float4*)(Lrow + (size_t)(i + 0) * 8 + half * 4);
  const float4 l1 = *(const float4*)(Lrow + (size_t)(i + 1) * 8 + half * 4);
  const float4 l2 = *(const float4*)(Lrow + (size_t)(i + 2) * 8 + half * 4);
  const float4 l3 = *(const float4*)(Lrow + (size_t)(i + 3) * 8 + half * 4);
  #pragma unroll
  for (int r = 0; r < 4; ++r) {
    const float a0 = ECOMP(l0, r), a1 = ECOMP(l1, r);
    const float a2 = ECOMP(l2, r), a3 = ECOMP(l3, r);
    float x = vk0[half * 4 + r];
    x = fmaf(a0, ea.x, x); x = fmaf(a1, ea.y, x);
    x = fmaf(a2, ea.z, x); x = fmaf(a3, ea.w, x);
    vk0[half * 4 + r] = x;
    float y = vk1[half * 4 + r];
    y = fmaf(a0, eb.x, y); y = fmaf(a1, eb.y, y);
    y = fmaf(a2, eb.z, y); y = fmaf(a3, eb.w, y);
    vk1[half * 4 + r] = y;
  }
}

// Phase 1: pivoted Cholesky (rank 8) of each G_n, L -> LDS, u = L^T z -> LDS.
// Phase 2: dist[n,k] = ||u_n - L_n^T e_k||^2, argmin over k (first-index ties).
__global__ __launch_bounds__(256, 4)
void kFactorDist(const float* __restrict__ z, const float* __restrict__ G,
                 const float* __restrict__ E, float* __restrict__ outIdxF,
                 int* __restrict__ outIdxI)
{
  __shared__ float sL[NB * LSTRIDE];
  __shared__ float sU[NB * 8];
  __shared__ float sMv[NB * 64];
  __shared__ int   sMi[NB * 64];

  const int tid  = threadIdx.x;
  const int wave = tid >> 6;
  const int lane = tid & 63;
  const int nblk = blockIdx.x;

  // ---------------- phase 1: each wave factors 2 rows ----------------
  for (int t2 = 0; t2 < 2; ++t2) {
    const int nl = wave * 2 + t2;
    const int n  = nblk * NB + nl;
    const size_t gb = (size_t)n * (ND * ND);
    const int i0 = lane, i1 = lane + 64;
    float d0 = G[gb + (size_t)i0 * ND + i0];
    float d1 = G[gb + (size_t)i1 * ND + i1];
    float L0[RANK], L1[RANK];
    #pragma unroll
    for (int j = 0; j < RANK; ++j) {
      // wave-wide argmax of the updated diagonal (pivot selection)
      float mv; int p;
      if (d1 > d0) { mv = d1; p = i1; } else { mv = d0; p = i0; }
      #pragma unroll
      for (int off = 32; off; off >>= 1) {
        const float ov = __shfl_xor(mv, off);
        const int   op = __shfl_xor(p, off);
        if (ov > mv || (ov == mv && op < p)) { mv = ov; p = op; }
      }
      const float s = (mv > 1e-12f) ? (1.0f / sqrtf(mv)) : 0.0f;
      // Schur column at pivot row p (G symmetric -> row == column)
      float c0 = G[gb + (size_t)p * ND + i0];
      float c1 = G[gb + (size_t)p * ND + i1];
      #pragma unroll
      for (int t = 0; t < j; ++t) {
        const float lsel = (p < 64) ? L0[t] : L1[t];
        const float lpt  = __shfl(lsel, p & 63);
        c0 -= L0[t] * lpt;
        c1 -= L1[t] * lpt;
      }
      const float l0 = c0 * s, l1 = c1 * s;
      L0[j] = l0; L1[j] = l1;
      d0 -= l0 * l0;
      d1 -= l1 * l1;
    }
    // store L rows to LDS
    float* lb = &sL[nl * LSTRIDE];
    #pragma unroll
    for (int r = 0; r < RANK; ++r) {
      lb[i0 * 8 + r] = L0[r];
      lb[i1 * 8 + r] = L1[r];
    }
    // u = L^T z (wave reduce)
    const float z0 = z[(size_t)n * ND + i0];
    const float z1 = z[(size_t)n * ND + i1];
    float pu[RANK];
    #pragma unroll
    for (int r = 0; r < RANK; ++r) pu[r] = L0[r] * z0 + L1[r] * z1;
    #pragma unroll
    for (int off = 32; off; off >>= 1) {
      #pragma unroll
      for (int r = 0; r < RANK; ++r) pu[r] += __shfl_xor(pu[r], off);
    }
    if (lane == 0) {
      #pragma unroll
      for (int r = 0; r < RANK; ++r) sU[nl * 8 + r] = pu[r];
    }
  }
  __syncthreads();

  // ---------------- phase 2: thread owns 2 n x 2 k ----------------
  const int npair = tid & 3;
  const int kg    = tid >> 2;            // 0..63
  const int na  = npair * 2;
  const int nb2 = npair * 2 + 1;
  float ua[RANK], ub[RANK];
  #pragma unroll
  for (int r = 0; r < RANK; ++r) { ua[r] = sU[na * 8 + r]; ub[r] = sU[nb2 * 8 + r]; }
  const float* La = &sL[na * LSTRIDE];
  const float* Lb = &sL[nb2 * LSTRIDE];
  float bva = 3.4e38f, bvb = 3.4e38f;
  int   bia = 0, bib = 0;

  for (int kp = 0; kp < 8; ++kp) {
    const int k0 = kp * 128 + kg * 2;
    float va[2][RANK], vb[2][RANK];
    #pragma unroll
    for (int kk = 0; kk < 2; ++kk)
      #pragma unroll
      for (int r = 0; r < RANK; ++r) { va[kk][r] = 0.f; vb[kk][r] = 0.f; }

    const float* e0 = E + (size_t)k0 * ND;
    const float* e1 = e0 + ND;
    #pragma unroll 2
    for (int ii = 0; ii < 32; ++ii) {
      const int i = ii * 4;
      const float4 ea = *(const float4*)(e0 + i);
      const float4 eb = *(const float4*)(e1 + i);
      #pragma unroll
      for (int half = 0; half < 2; ++half) {
        accum_pair(La, i, half, ea, eb, &va[0][0], &va[1][0]);
        accum_pair(Lb, i, half, ea, eb, &vb[0][0], &vb[1][0]);
      }
    }
    #pragma unroll
    for (int kk = 0; kk < 2; ++kk) {
      float da = 0.f, db = 0.f;
      #pragma unroll
      for (int r = 0; r < RANK; ++r) {
        const float ta = ua[r] - va[kk][r]; da = fmaf(ta, ta, da);
        const float tb = ub[r] - vb[kk][r]; db = fmaf(tb, tb, db);
      }
      const int k = k0 + kk;
      if (da < bva) { bva = da; bia = k; }   // ascending k -> earliest index kept
      if (db < bvb) { bvb = db; bib = k; }
    }
  }
  sMv[na  * 64 + kg] = bva; sMi[na  * 64 + kg] = bia;
  sMv[nb2 * 64 + kg] = bvb; sMi[nb2 * 64 + kg] = bib;
  __syncthreads();

  if (tid < NB) {
    float bv = 3.4e38f; int bi = 1 << 30;
    for (int g = 0; g < 64; ++g) {
      const float v = sMv[tid * 64 + g];
      const int   i = sMi[tid * 64 + g];
      if (v < bv || (v == bv && i < bi)) { bv = v; bi = i; }
    }
    const int n = nblk * NB + tid;
    outIdxI[n] = bi;
    outIdxF[n] = (float)bi;
  }
}

// one wave per n: scatter counts and dw
__global__ __launch_bounds__(256)
void kScatter(const float* __restrict__ z, const int* __restrict__ idx,
              float* __restrict__ counts, float* __restrict__ dw)
{
  const int wave = threadIdx.x >> 6, lane = threadIdx.x & 63;
  const int n = blockIdx.x * 4 + wave;
  const int k = idx[n];
  const float z0 = z[(size_t)n * ND + lane];
  const float z1 = z[(size_t)n * ND + lane + 64];
  atomicAdd(&dw[k * ND + lane], z0);
  atomicAdd(&dw[k * ND + lane + 64], z1);
  if (lane == 0) atomicAdd(&counts[k], 1.0f);
}

__global__ __launch_bounds__(1024)
void kCs(const float* __restrict__ cs, const float* __restrict__ counts,
         float* __restrict__ outCs, float* __restrict__ ntot)
{
  __shared__ float red[16];
  const int k = threadIdx.x;
  const float v = cs[k] * 0.99f + 0.01f * counts[k];
  outCs[k] = v;
  float s = v;
  #pragma unroll
  for (int off = 32; off; off >>= 1) s += __shfl_xor(s, off);
  const int wv = k >> 6, lane = k & 63;
  if (lane == 0) red[wv] = s;
  __syncthreads();
  if (k == 0) {
    float t = 0.f;
    #pragma unroll
    for (int w = 0; w < 16; ++w) t += red[w];
    ntot[0] = t;
  }
}

__global__ __launch_bounds__(256)
void kEma(const float* __restrict__ emaw, const float* __restrict__ dw,
          const float* __restrict__ newCs, const float* __restrict__ ntot,
          float* __restrict__ outEmb, float* __restrict__ outEma)
{
  const int e = blockIdx.x * 256 + threadIdx.x;   // 0..131071
  const int k = e >> 7;
  const float nv = emaw[e] * 0.99f + 0.01f * dw[e];
  outEma[e] = nv;
  const float nt = ntot[0];
  const float sm = (newCs[k] + 1e-5f) / (nt + 1024.0f * 1e-5f) * nt;
  outEmb[e] = nv / sm;
}

extern "C" void kernel_launch(void* const* d_in, const int* in_sizes, int n_in,
                              void* d_out, int out_size, void* d_ws, size_t ws_size,
                              hipStream_t stream)
{
  const float* z  = (const float*)d_in[0];
  const float* G  = (const float*)d_in[1];
  const float* E  = (const float*)d_in[2];
  const float* cs = (const float*)d_in[3];
  const float* ew = (const float*)d_in[4];
  float* out = (float*)d_out;

  char*  ws      = (char*)d_ws;
  int*   wIdx    = (int*)(ws + WSB_IDX);
  float* wCounts = (float*)(ws + WSB_COUNTS);
  float* wDw     = (float*)(ws + WSB_DW);
  float* wNtot   = (float*)(ws + WSB_NTOT);

  // zero counts + dw + ntot (contiguous) — required every call (atomics)
  hipMemsetAsync(wCounts, 0, (size_t)(1024 + 131072 + 1) * sizeof(float), stream);

  kFactorDist<<<NROWS / NB, 256, 0, stream>>>(z, G, E, out, wIdx);
  kScatter  <<<NROWS / 4,   256, 0, stream>>>(z, wIdx, wCounts, wDw);
  kCs       <<<1,          1024, 0, stream>>>(cs, wCounts, out + OFF_CS, wNtot);
  kEma      <<<131072/256,  256, 0, stream>>>(ew, wDw, out + OFF_CS, wNtot,
                                              out + OFF_EMB, out + OFF_EMA);
}

// Round 2
// 261.106 us; speedup vs baseline: 1.3420x; 1.3420x over previous
//
#include <hip/hip_runtime.h>
#include <cstdint>
#include <cstddef>

#define ND    128
#define NK    1024
#define NROWS 8192
#define NB    8        // rows (n) per block in kFactorDist
#define RANK  8
#define LSTRIDE 1028   // 128*8 + 4 pad floats per n

#define OFF_EMB 8192
#define OFF_CS  139264
#define OFF_EMA 140288

// workspace byte offsets
#define WSB_IDX    0
#define WSB_COUNTS (8192 * 4)
#define WSB_DW     (WSB_COUNTS + 1024 * 4)     // dw AND (earlier in stream) ET share this 512KB
#define WSB_NTOT   (WSB_DW + 131072 * 4)

#define ECOMP(v4, c) ((c)==0 ? (v4).x : (c)==1 ? (v4).y : (c)==2 ? (v4).z : (v4).w)

// ---------------- E transpose: ET[i][k] = E[k][i], 128 x 1024 ----------------
__global__ __launch_bounds__(256)
void kT(const float* __restrict__ E, float* __restrict__ ET)
{
  __shared__ float tile[32][33];
  const int bk = blockIdx.x;           // k-tile 0..31
  const int bi = blockIdx.y;           // i-tile 0..3
  const int tx = threadIdx.x & 31;
  const int ty = threadIdx.x >> 5;     // 0..7
  #pragma unroll
  for (int r = 0; r < 32; r += 8)
    tile[ty + r][tx] = E[(size_t)(bk * 32 + ty + r) * ND + bi * 32 + tx];
  __syncthreads();
  #pragma unroll
  for (int r = 0; r < 32; r += 8)
    ET[(size_t)(bi * 32 + ty + r) * NK + bk * 32 + tx] = tile[tx][ty + r];
}

// Phase 1: pivoted Cholesky (rank 8) of each G_n -> L in LDS, u = L^T z.
// Phase 2: wave-task (n, k-half): lane owns 8 k; L broadcast from LDS,
//          e from ET (coalesced). dist = ||u - L^T e||^2, argmin (first-idx ties).
__global__ __launch_bounds__(256, 4)
void kFactorDist(const float* __restrict__ z, const float* __restrict__ G,
                 const float* __restrict__ ET, float* __restrict__ outIdxF,
                 int* __restrict__ outIdxI)
{
  __shared__ float sL[NB * LSTRIDE];
  __shared__ float sU[NB * 8];
  __shared__ float sTv[16];
  __shared__ int   sTi[16];

  const int tid  = threadIdx.x;
  const int wave = tid >> 6;
  const int lane = tid & 63;
  const int nblk = blockIdx.x;

  // ---------------- phase 1: each wave factors 2 rows ----------------
  for (int t2 = 0; t2 < 2; ++t2) {
    const int nl = wave * 2 + t2;
    const int n  = nblk * NB + nl;
    const size_t gb = (size_t)n * (ND * ND);
    const int i0 = lane, i1 = lane + 64;
    float d0 = G[gb + (size_t)i0 * ND + i0];
    float d1 = G[gb + (size_t)i1 * ND + i1];
    float L0[RANK], L1[RANK];
    #pragma unroll
    for (int j = 0; j < RANK; ++j) {
      float mv; int p;
      if (d1 > d0) { mv = d1; p = i1; } else { mv = d0; p = i0; }
      #pragma unroll
      for (int off = 32; off; off >>= 1) {
        const float ov = __shfl_xor(mv, off);
        const int   op = __shfl_xor(p, off);
        if (ov > mv || (ov == mv && op < p)) { mv = ov; p = op; }
      }
      const float s = (mv > 1e-12f) ? (1.0f / sqrtf(mv)) : 0.0f;
      float c0 = G[gb + (size_t)p * ND + i0];
      float c1 = G[gb + (size_t)p * ND + i1];
      #pragma unroll
      for (int t = 0; t < j; ++t) {
        const float lsel = (p < 64) ? L0[t] : L1[t];
        const float lpt  = __shfl(lsel, p & 63);
        c0 -= L0[t] * lpt;
        c1 -= L1[t] * lpt;
      }
      const float l0 = c0 * s, l1 = c1 * s;
      L0[j] = l0; L1[j] = l1;
      d0 -= l0 * l0;
      d1 -= l1 * l1;
    }
    float* lb = &sL[nl * LSTRIDE];
    #pragma unroll
    for (int r = 0; r < RANK; ++r) {
      lb[i0 * 8 + r] = L0[r];
      lb[i1 * 8 + r] = L1[r];
    }
    const float z0 = z[(size_t)n * ND + i0];
    const float z1 = z[(size_t)n * ND + i1];
    float pu[RANK];
    #pragma unroll
    for (int r = 0; r < RANK; ++r) pu[r] = L0[r] * z0 + L1[r] * z1;
    #pragma unroll
    for (int off = 32; off; off >>= 1) {
      #pragma unroll
      for (int r = 0; r < RANK; ++r) pu[r] += __shfl_xor(pu[r], off);
    }
    if (lane == 0) {
      #pragma unroll
      for (int r = 0; r < RANK; ++r) sU[nl * 8 + r] = pu[r];
    }
  }
  __syncthreads();

  // ---------------- phase 2: 16 wave-tasks (n, khalf), 4 per wave ----------------
  for (int t = 0; t < 4; ++t) {
    const int task  = wave * 4 + t;
    const int nl    = task >> 1;
    const int khalf = task & 1;
    const float* lb  = &sL[nl * LSTRIDE];
    const float* etA = ET + (size_t)khalf * 512 + lane * 4;
    const float* etB = etA + 256;

    float aA[4][RANK], aB[4][RANK];
    #pragma unroll
    for (int j = 0; j < 4; ++j)
      #pragma unroll
      for (int r = 0; r < RANK; ++r) { aA[j][r] = 0.f; aB[j][r] = 0.f; }

    #pragma unroll 2
    for (int i = 0; i < ND; ++i) {
      const float4 l0 = *(const float4*)(lb + (size_t)i * 8);
      const float4 l1 = *(const float4*)(lb + (size_t)i * 8 + 4);
      const float4 ea = *(const float4*)(etA + (size_t)i * NK);
      const float4 eb = *(const float4*)(etB + (size_t)i * NK);
      #pragma unroll
      for (int j = 0; j < 4; ++j) {
        const float va = ECOMP(ea, j);
        const float vb = ECOMP(eb, j);
        aA[j][0] = fmaf(l0.x, va, aA[j][0]);
        aA[j][1] = fmaf(l0.y, va, aA[j][1]);
        aA[j][2] = fmaf(l0.z, va, aA[j][2]);
        aA[j][3] = fmaf(l0.w, va, aA[j][3]);
        aA[j][4] = fmaf(l1.x, va, aA[j][4]);
        aA[j][5] = fmaf(l1.y, va, aA[j][5]);
        aA[j][6] = fmaf(l1.z, va, aA[j][6]);
        aA[j][7] = fmaf(l1.w, va, aA[j][7]);
        aB[j][0] = fmaf(l0.x, vb, aB[j][0]);
        aB[j][1] = fmaf(l0.y, vb, aB[j][1]);
        aB[j][2] = fmaf(l0.z, vb, aB[j][2]);
        aB[j][3] = fmaf(l0.w, vb, aB[j][3]);
        aB[j][4] = fmaf(l1.x, vb, aB[j][4]);
        aB[j][5] = fmaf(l1.y, vb, aB[j][5]);
        aB[j][6] = fmaf(l1.z, vb, aB[j][6]);
        aB[j][7] = fmaf(l1.w, vb, aB[j][7]);
      }
    }

    float u[RANK];
    #pragma unroll
    for (int r = 0; r < RANK; ++r) u[r] = sU[nl * 8 + r];

    float bv = 3.4e38f; int bi = 1 << 30;
    #pragma unroll
    for (int j = 0; j < 4; ++j) {
      float d = 0.f;
      #pragma unroll
      for (int r = 0; r < RANK; ++r) { const float tdiff = u[r] - aA[j][r]; d = fmaf(tdiff, tdiff, d); }
      const int k = khalf * 512 + lane * 4 + j;
      if (d < bv) { bv = d; bi = k; }
    }
    #pragma unroll
    for (int j = 0; j < 4; ++j) {
      float d = 0.f;
      #pragma unroll
      for (int r = 0; r < RANK; ++r) { const float tdiff = u[r] - aB[j][r]; d = fmaf(tdiff, tdiff, d); }
      const int k = khalf * 512 + 256 + lane * 4 + j;
      if (d < bv) { bv = d; bi = k; }
    }
    // in-wave argmin with first-index tie-break
    #pragma unroll
    for (int off = 32; off; off >>= 1) {
      const float ov = __shfl_xor(bv, off);
      const int   oi = __shfl_xor(bi, off);
      if (ov < bv || (ov == bv && oi < bi)) { bv = ov; bi = oi; }
    }
    if (lane == 0) { sTv[task] = bv; sTi[task] = bi; }
  }
  __syncthreads();

  if (tid < NB) {
    // combine khalf 0/1; khalf0 indices are all smaller -> strict < keeps ties at khalf0
    const float v0 = sTv[tid * 2], v1 = sTv[tid * 2 + 1];
    const int   i0 = sTi[tid * 2], i1 = sTi[tid * 2 + 1];
    const int   bi = (v1 < v0) ? i1 : i0;
    const int n = nblk * NB + tid;
    outIdxI[n] = bi;
    outIdxF[n] = (float)bi;
  }
}

// one wave per n: scatter counts and dw
__global__ __launch_bounds__(256)
void kScatter(const float* __restrict__ z, const int* __restrict__ idx,
              float* __restrict__ counts, float* __restrict__ dw)
{
  const int wave = threadIdx.x >> 6, lane = threadIdx.x & 63;
  const int n = blockIdx.x * 4 + wave;
  const int k = idx[n];
  const float z0 = z[(size_t)n * ND + lane];
  const float z1 = z[(size_t)n * ND + lane + 64];
  atomicAdd(&dw[k * ND + lane], z0);
  atomicAdd(&dw[k * ND + lane + 64], z1);
  if (lane == 0) atomicAdd(&counts[k], 1.0f);
}

__global__ __launch_bounds__(1024)
void kCs(const float* __restrict__ cs, const float* __restrict__ counts,
         float* __restrict__ outCs, float* __restrict__ ntot)
{
  __shared__ float red[16];
  const int k = threadIdx.x;
  const float v = cs[k] * 0.99f + 0.01f * counts[k];
  outCs[k] = v;
  float s = v;
  #pragma unroll
  for (int off = 32; off; off >>= 1) s += __shfl_xor(s, off);
  const int wv = k >> 6, lane = k & 63;
  if (lane == 0) red[wv] = s;
  __syncthreads();
  if (k == 0) {
    float t = 0.f;
    #pragma unroll
    for (int w = 0; w < 16; ++w) t += red[w];
    ntot[0] = t;
  }
}

__global__ __launch_bounds__(256)
void kEma(const float* __restrict__ emaw, const float* __restrict__ dw,
          const float* __restrict__ newCs, const float* __restrict__ ntot,
          float* __restrict__ outEmb, float* __restrict__ outEma)
{
  const int e = blockIdx.x * 256 + threadIdx.x;   // 0..131071
  const int k = e >> 7;
  const float nv = emaw[e] * 0.99f + 0.01f * dw[e];
  outEma[e] = nv;
  const float nt = ntot[0];
  const float sm = (newCs[k] + 1e-5f) / (nt + 1024.0f * 1e-5f) * nt;
  outEmb[e] = nv / sm;
}

extern "C" void kernel_launch(void* const* d_in, const int* in_sizes, int n_in,
                              void* d_out, int out_size, void* d_ws, size_t ws_size,
                              hipStream_t stream)
{
  const float* z  = (const float*)d_in[0];
  const float* G  = (const float*)d_in[1];
  const float* E  = (const float*)d_in[2];
  const float* cs = (const float*)d_in[3];
  const float* ew = (const float*)d_in[4];
  float* out = (float*)d_out;

  char*  ws      = (char*)d_ws;
  int*   wIdx    = (int*)(ws + WSB_IDX);
  float* wCounts = (float*)(ws + WSB_COUNTS);
  float* wET     = (float*)(ws + WSB_DW);   // ET while kFactorDist runs
  float* wDw     = (float*)(ws + WSB_DW);   // dw afterwards (memset below)
  float* wNtot   = (float*)(ws + WSB_NTOT);

  // 1) transpose E -> ET[i][k]
  kT<<<dim3(32, 4), 256, 0, stream>>>(E, wET);
  // 2) factor + distances + argmin
  kFactorDist<<<NROWS / NB, 256, 0, stream>>>(z, G, wET, out, wIdx);
  // 3) zero counts + dw + ntot (AFTER kFactorDist: dw aliases ET)
  hipMemsetAsync(wCounts, 0, (size_t)(1024 + 131072 + 1) * sizeof(float), stream);
  // 4) scatter + EMA epilogue
  kScatter<<<NROWS / 4,   256, 0, stream>>>(z, wIdx, wCounts, wDw);
  kCs     <<<1,          1024, 0, stream>>>(cs, wCounts, out + OFF_CS, wNtot);
  kEma    <<<131072/256,  256, 0, stream>>>(ew, wDw, out + OFF_CS, wNtot,
                                            out + OFF_EMB, out + OFF_EMA);
}

// Round 3
// 255.918 us; speedup vs baseline: 1.3692x; 1.0203x over previous
//
#include <hip/hip_runtime.h>
#include <cstdint>
#include <cstddef>

#define ND    128
#define NK    1024
#define NROWS 8192
#define NB    8        // rows (n) per block in kFactorDist
#define RANK  8
#define LSTRIDE 1028   // 128*8 + 4 pad floats per n

#define OFF_EMB 8192
#define OFF_CS  139264
#define OFF_EMA 140288

// workspace byte offsets
#define WSB_IDX    0
#define WSB_COUNTS (8192 * 4)
#define WSB_DW     (WSB_COUNTS + 1024 * 4)     // dw AND (earlier in stream) ET share this 512KB
#define WSB_NTOT   (WSB_DW + 131072 * 4)

#define ECOMP(v4, c) ((c)==0 ? (v4).x : (c)==1 ? (v4).y : (c)==2 ? (v4).z : (v4).w)

#define FMA8(acc, l0, l1, s) \
  acc[0]=fmaf((l0).x,(s),acc[0]); acc[1]=fmaf((l0).y,(s),acc[1]); \
  acc[2]=fmaf((l0).z,(s),acc[2]); acc[3]=fmaf((l0).w,(s),acc[3]); \
  acc[4]=fmaf((l1).x,(s),acc[4]); acc[5]=fmaf((l1).y,(s),acc[5]); \
  acc[6]=fmaf((l1).z,(s),acc[6]); acc[7]=fmaf((l1).w,(s),acc[7]);

// ---------------- E transpose: ET[i][k] = E[k][i], 128 x 1024 ----------------
__global__ __launch_bounds__(256)
void kT(const float* __restrict__ E, float* __restrict__ ET)
{
  __shared__ float tile[32][33];
  const int bk = blockIdx.x;           // k-tile 0..31
  const int bi = blockIdx.y;           // i-tile 0..3
  const int tx = threadIdx.x & 31;
  const int ty = threadIdx.x >> 5;     // 0..7
  #pragma unroll
  for (int r = 0; r < 32; r += 8)
    tile[ty + r][tx] = E[(size_t)(bk * 32 + ty + r) * ND + bi * 32 + tx];
  __syncthreads();
  #pragma unroll
  for (int r = 0; r < 32; r += 8)
    ET[(size_t)(bi * 32 + ty + r) * NK + bk * 32 + tx] = tile[tx][ty + r];
}

// Phase 1: pivoted Cholesky (rank 8) of each G_n -> L in LDS, u = L^T z.
// Phase 2: wave-task (n-pair, k-half): lane owns 8 k x 2 n; L broadcast from LDS,
//          e from ET (coalesced, L2-resident, reused across both n).
__global__ __launch_bounds__(256, 2)
void kFactorDist(const float* __restrict__ z, const float* __restrict__ G,
                 const float* __restrict__ ET, float* __restrict__ outIdxF,
                 int* __restrict__ outIdxI)
{
  __shared__ float sL[NB * LSTRIDE];
  __shared__ float sU[NB * 8];
  __shared__ float sTv[16];
  __shared__ int   sTi[16];

  const int tid  = threadIdx.x;
  const int wave = tid >> 6;
  const int lane = tid & 63;
  const int nblk = blockIdx.x;

  // ---------------- phase 1: each wave factors 2 rows ----------------
  for (int t2 = 0; t2 < 2; ++t2) {
    const int nl = wave * 2 + t2;
    const int n  = nblk * NB + nl;
    const size_t gb = (size_t)n * (ND * ND);
    const int i0 = lane, i1 = lane + 64;
    float d0 = G[gb + (size_t)i0 * ND + i0];
    float d1 = G[gb + (size_t)i1 * ND + i1];
    float L0[RANK], L1[RANK];
    #pragma unroll
    for (int j = 0; j < RANK; ++j) {
      float mv; int p;
      if (d1 > d0) { mv = d1; p = i1; } else { mv = d0; p = i0; }
      #pragma unroll
      for (int off = 32; off; off >>= 1) {
        const float ov = __shfl_xor(mv, off);
        const int   op = __shfl_xor(p, off);
        if (ov > mv || (ov == mv && op < p)) { mv = ov; p = op; }
      }
      const float s = (mv > 1e-12f) ? (1.0f / sqrtf(mv)) : 0.0f;
      float c0 = G[gb + (size_t)p * ND + i0];
      float c1 = G[gb + (size_t)p * ND + i1];
      #pragma unroll
      for (int t = 0; t < j; ++t) {
        const float lsel = (p < 64) ? L0[t] : L1[t];
        const float lpt  = __shfl(lsel, p & 63);
        c0 -= L0[t] * lpt;
        c1 -= L1[t] * lpt;
      }
      const float l0 = c0 * s, l1 = c1 * s;
      L0[j] = l0; L1[j] = l1;
      d0 -= l0 * l0;
      d1 -= l1 * l1;
    }
    float* lb = &sL[nl * LSTRIDE];
    #pragma unroll
    for (int r = 0; r < RANK; ++r) {
      lb[i0 * 8 + r] = L0[r];
      lb[i1 * 8 + r] = L1[r];
    }
    const float z0 = z[(size_t)n * ND + i0];
    const float z1 = z[(size_t)n * ND + i1];
    float pu[RANK];
    #pragma unroll
    for (int r = 0; r < RANK; ++r) pu[r] = L0[r] * z0 + L1[r] * z1;
    #pragma unroll
    for (int off = 32; off; off >>= 1) {
      #pragma unroll
      for (int r = 0; r < RANK; ++r) pu[r] += __shfl_xor(pu[r], off);
    }
    if (lane == 0) {
      #pragma unroll
      for (int r = 0; r < RANK; ++r) sU[nl * 8 + r] = pu[r];
    }
  }
  __syncthreads();

  // -------- phase 2: 8 wave-tasks (n-pair, khalf), 2 per wave, 2 n each --------
  for (int t = 0; t < 2; ++t) {
    const int task  = wave * 2 + t;
    const int npair = task >> 1;
    const int khalf = task & 1;
    const int n0l = npair * 2, n1l = npair * 2 + 1;
    const float* lb0 = &sL[n0l * LSTRIDE];
    const float* lb1 = &sL[n1l * LSTRIDE];
    const float* etA = ET + (size_t)khalf * 512 + lane * 4;
    const float* etB = etA + 256;

    float a0A[4][RANK], a0B[4][RANK], a1A[4][RANK], a1B[4][RANK];
    #pragma unroll
    for (int j = 0; j < 4; ++j)
      #pragma unroll
      for (int r = 0; r < RANK; ++r) {
        a0A[j][r] = 0.f; a0B[j][r] = 0.f; a1A[j][r] = 0.f; a1B[j][r] = 0.f;
      }

    #pragma unroll 2
    for (int i = 0; i < ND; ++i) {
      const float4 p0 = *(const float4*)(lb0 + (size_t)i * 8);
      const float4 q0 = *(const float4*)(lb0 + (size_t)i * 8 + 4);
      const float4 p1 = *(const float4*)(lb1 + (size_t)i * 8);
      const float4 q1 = *(const float4*)(lb1 + (size_t)i * 8 + 4);
      const float4 ea = *(const float4*)(etA + (size_t)i * NK);
      const float4 eb = *(const float4*)(etB + (size_t)i * NK);
      #pragma unroll
      for (int j = 0; j < 4; ++j) {
        const float va = ECOMP(ea, j);
        const float vb = ECOMP(eb, j);
        FMA8(a0A[j], p0, q0, va);
        FMA8(a0B[j], p0, q0, vb);
        FMA8(a1A[j], p1, q1, va);
        FMA8(a1B[j], p1, q1, vb);
      }
    }

    float u0[RANK], u1[RANK];
    #pragma unroll
    for (int r = 0; r < RANK; ++r) { u0[r] = sU[n0l * 8 + r]; u1[r] = sU[n1l * 8 + r]; }

    float bv0 = 3.4e38f, bv1 = 3.4e38f;
    int   bi0 = 1 << 30, bi1 = 1 << 30;
    const int kbase = khalf * 512 + lane * 4;
    #pragma unroll
    for (int j = 0; j < 4; ++j) {
      float d0 = 0.f, d1 = 0.f;
      #pragma unroll
      for (int r = 0; r < RANK; ++r) {
        const float t0 = u0[r] - a0A[j][r]; d0 = fmaf(t0, t0, d0);
        const float t1 = u1[r] - a1A[j][r]; d1 = fmaf(t1, t1, d1);
      }
      const int k = kbase + j;
      if (d0 < bv0) { bv0 = d0; bi0 = k; }
      if (d1 < bv1) { bv1 = d1; bi1 = k; }
    }
    #pragma unroll
    for (int j = 0; j < 4; ++j) {
      float d0 = 0.f, d1 = 0.f;
      #pragma unroll
      for (int r = 0; r < RANK; ++r) {
        const float t0 = u0[r] - a0B[j][r]; d0 = fmaf(t0, t0, d0);
        const float t1 = u1[r] - a1B[j][r]; d1 = fmaf(t1, t1, d1);
      }
      const int k = kbase + 256 + j;
      if (d0 < bv0) { bv0 = d0; bi0 = k; }
      if (d1 < bv1) { bv1 = d1; bi1 = k; }
    }
    // in-wave argmin with first-index tie-break
    #pragma unroll
    for (int off = 32; off; off >>= 1) {
      const float ov0 = __shfl_xor(bv0, off);
      const int   oi0 = __shfl_xor(bi0, off);
      if (ov0 < bv0 || (ov0 == bv0 && oi0 < bi0)) { bv0 = ov0; bi0 = oi0; }
      const float ov1 = __shfl_xor(bv1, off);
      const int   oi1 = __shfl_xor(bi1, off);
      if (ov1 < bv1 || (ov1 == bv1 && oi1 < bi1)) { bv1 = ov1; bi1 = oi1; }
    }
    if (lane == 0) {
      sTv[n0l * 2 + khalf] = bv0; sTi[n0l * 2 + khalf] = bi0;
      sTv[n1l * 2 + khalf] = bv1; sTi[n1l * 2 + khalf] = bi1;
    }
  }
  __syncthreads();

  if (tid < NB) {
    // combine khalf 0/1; khalf0 indices are all smaller -> strict < keeps ties at khalf0
    const float v0 = sTv[tid * 2], v1 = sTv[tid * 2 + 1];
    const int   i0 = sTi[tid * 2], i1 = sTi[tid * 2 + 1];
    const int   bi = (v1 < v0) ? i1 : i0;
    const int n = nblk * NB + tid;
    outIdxI[n] = bi;
    outIdxF[n] = (float)bi;
  }
}

// one wave per n: scatter counts and dw
__global__ __launch_bounds__(256)
void kScatter(const float* __restrict__ z, const int* __restrict__ idx,
              float* __restrict__ counts, float* __restrict__ dw)
{
  const int wave = threadIdx.x >> 6, lane = threadIdx.x & 63;
  const int n = blockIdx.x * 4 + wave;
  const int k = idx[n];
  const float z0 = z[(size_t)n * ND + lane];
  const float z1 = z[(size_t)n * ND + lane + 64];
  atomicAdd(&dw[k * ND + lane], z0);
  atomicAdd(&dw[k * ND + lane + 64], z1);
  if (lane == 0) atomicAdd(&counts[k], 1.0f);
}

__global__ __launch_bounds__(1024)
void kCs(const float* __restrict__ cs, const float* __restrict__ counts,
         float* __restrict__ outCs, float* __restrict__ ntot)
{
  __shared__ float red[16];
  const int k = threadIdx.x;
  const float v = cs[k] * 0.99f + 0.01f * counts[k];
  outCs[k] = v;
  float s = v;
  #pragma unroll
  for (int off = 32; off; off >>= 1) s += __shfl_xor(s, off);
  const int wv = k >> 6, lane = k & 63;
  if (lane == 0) red[wv] = s;
  __syncthreads();
  if (k == 0) {
    float t = 0.f;
    #pragma unroll
    for (int w = 0; w < 16; ++w) t += red[w];
    ntot[0] = t;
  }
}

__global__ __launch_bounds__(256)
void kEma(const float* __restrict__ emaw, const float* __restrict__ dw,
          const float* __restrict__ newCs, const float* __restrict__ ntot,
          float* __restrict__ outEmb, float* __restrict__ outEma)
{
  const int e = blockIdx.x * 256 + threadIdx.x;   // 0..131071
  const int k = e >> 7;
  const float nv = emaw[e] * 0.99f + 0.01f * dw[e];
  outEma[e] = nv;
  const float nt = ntot[0];
  const float sm = (newCs[k] + 1e-5f) / (nt + 1024.0f * 1e-5f) * nt;
  outEmb[e] = nv / sm;
}

extern "C" void kernel_launch(void* const* d_in, const int* in_sizes, int n_in,
                              void* d_out, int out_size, void* d_ws, size_t ws_size,
                              hipStream_t stream)
{
  const float* z  = (const float*)d_in[0];
  const float* G  = (const float*)d_in[1];
  const float* E  = (const float*)d_in[2];
  const float* cs = (const float*)d_in[3];
  const float* ew = (const float*)d_in[4];
  float* out = (float*)d_out;

  char*  ws      = (char*)d_ws;
  int*   wIdx    = (int*)(ws + WSB_IDX);
  float* wCounts = (float*)(ws + WSB_COUNTS);
  float* wET     = (float*)(ws + WSB_DW);   // ET while kFactorDist runs
  float* wDw     = (float*)(ws + WSB_DW);   // dw afterwards (memset below)
  float* wNtot   = (float*)(ws + WSB_NTOT);

  // 1) transpose E -> ET[i][k]
  kT<<<dim3(32, 4), 256, 0, stream>>>(E, wET);
  // 2) factor + distances + argmin
  kFactorDist<<<NROWS / NB, 256, 0, stream>>>(z, G, wET, out, wIdx);
  // 3) zero counts + dw + ntot (AFTER kFactorDist: dw aliases ET)
  hipMemsetAsync(wCounts, 0, (size_t)(1024 + 131072 + 1) * sizeof(float), stream);
  // 4) scatter + EMA epilogue
  kScatter<<<NROWS / 4,   256, 0, stream>>>(z, wIdx, wCounts, wDw);
  kCs     <<<1,          1024, 0, stream>>>(cs, wCounts, out + OFF_CS, wNtot);
  kEma    <<<131072/256,  256, 0, stream>>>(ew, wDw, out + OFF_CS, wNtot,
                                            out + OFF_EMB, out + OFF_EMA);
}

// Round 4
// 242.394 us; speedup vs baseline: 1.4456x; 1.0558x over previous
//
#include <hip/hip_runtime.h>
#include <cstdint>
#include <cstddef>

#define ND    128
#define NK    1024
#define NROWS 8192
#define NB    8
#define RANK  8

#define OFF_EMB 8192
#define OFF_CS  139264
#define OFF_EMA 140288

// workspace byte offsets (16B-aligned)
#define WSB_LPACK  0                         // 8192*1024*4 = 32 MB
#define WSB_UPACK  33554432                  // 8192*8*4 = 256 KB
#define WSB_ET     33816576                  // 128*1024*4 = 512 KB
#define WSB_NTOT   34340864                  // 4 B (pad to 256)
#define WSB_COUNTS 34341120                  // 1024*4
#define WSB_DW     34345216                  // 131072*4
// counts+dw = 132096 floats = 33024 float4, zeroed by kPre blocks

#define ECOMP(v4, c) ((c)==0 ? (v4).x : (c)==1 ? (v4).y : (c)==2 ? (v4).z : (v4).w)

#define FMA8(acc, l0, l1, s) \
  acc[0]=fmaf((l0).x,(s),acc[0]); acc[1]=fmaf((l0).y,(s),acc[1]); \
  acc[2]=fmaf((l0).z,(s),acc[2]); acc[3]=fmaf((l0).w,(s),acc[3]); \
  acc[4]=fmaf((l1).x,(s),acc[4]); acc[5]=fmaf((l1).y,(s),acc[5]); \
  acc[6]=fmaf((l1).z,(s),acc[6]); acc[7]=fmaf((l1).w,(s),acc[7]);

// ---------------------------------------------------------------------------
// kPre: blocks 0..1023   : pivoted Cholesky, 1 wave per n (8 n / block)
//       blocks 1024..1151: E transpose -> ET[i][k]
//       block  1152      : ntot = 0.99*sum(cs) + 0.01*8192
//       blocks 1153..1217: zero counts+dw (33024 float4)
// ---------------------------------------------------------------------------
__global__ __launch_bounds__(512)
void kPre(const float* __restrict__ z, const float* __restrict__ G,
          const float* __restrict__ E, const float* __restrict__ cs,
          float* __restrict__ Lpack, float* __restrict__ uPack,
          float* __restrict__ ET, float* __restrict__ ntot,
          float* __restrict__ zeroReg)
{
  __shared__ float tile[32][33];
  __shared__ float red[8];
  const int b   = blockIdx.x;
  const int tid = threadIdx.x;

  if (b < 1024) {
    // ---- rank-8 pivoted Cholesky of G_n; one wave per n ----
    const int wave = tid >> 6, lane = tid & 63;
    const int n = b * 8 + wave;
    const size_t gb = (size_t)n * (ND * ND);
    const int i0 = lane, i1 = lane + 64;
    float d0 = G[gb + (size_t)i0 * ND + i0];
    float d1 = G[gb + (size_t)i1 * ND + i1];
    float L0[RANK], L1[RANK];
    #pragma unroll
    for (int j = 0; j < RANK; ++j) {
      float mv; int p;
      if (d1 > d0) { mv = d1; p = i1; } else { mv = d0; p = i0; }
      #pragma unroll
      for (int off = 32; off; off >>= 1) {
        const float ov = __shfl_xor(mv, off);
        const int   op = __shfl_xor(p, off);
        if (ov > mv || (ov == mv && op < p)) { mv = ov; p = op; }
      }
      const float s = (mv > 1e-12f) ? (1.0f / sqrtf(mv)) : 0.0f;
      float c0 = G[gb + (size_t)p * ND + i0];
      float c1 = G[gb + (size_t)p * ND + i1];
      #pragma unroll
      for (int t = 0; t < j; ++t) {
        const float lsel = (p < 64) ? L0[t] : L1[t];
        const float lpt  = __shfl(lsel, p & 63);
        c0 -= L0[t] * lpt;
        c1 -= L1[t] * lpt;
      }
      const float l0 = c0 * s, l1 = c1 * s;
      L0[j] = l0; L1[j] = l1;
      d0 -= l0 * l0;
      d1 -= l1 * l1;
    }
    // store L rows: Lpack[n][i*8+r], two float4 per i
    float* lb = Lpack + (size_t)n * 1024;
    float4 v;
    v.x=L0[0]; v.y=L0[1]; v.z=L0[2]; v.w=L0[3]; *(float4*)(lb + i0*8)     = v;
    v.x=L0[4]; v.y=L0[5]; v.z=L0[6]; v.w=L0[7]; *(float4*)(lb + i0*8 + 4) = v;
    v.x=L1[0]; v.y=L1[1]; v.z=L1[2]; v.w=L1[3]; *(float4*)(lb + i1*8)     = v;
    v.x=L1[4]; v.y=L1[5]; v.z=L1[6]; v.w=L1[7]; *(float4*)(lb + i1*8 + 4) = v;
    // u = L^T z (wave reduce)
    const float z0 = z[(size_t)n * ND + i0];
    const float z1 = z[(size_t)n * ND + i1];
    float pu[RANK];
    #pragma unroll
    for (int r = 0; r < RANK; ++r) pu[r] = L0[r] * z0 + L1[r] * z1;
    #pragma unroll
    for (int off = 32; off; off >>= 1) {
      #pragma unroll
      for (int r = 0; r < RANK; ++r) pu[r] += __shfl_xor(pu[r], off);
    }
    if (lane == 0) {
      float4 u0; u0.x=pu[0]; u0.y=pu[1]; u0.z=pu[2]; u0.w=pu[3];
      float4 u1; u1.x=pu[4]; u1.y=pu[5]; u1.z=pu[6]; u1.w=pu[7];
      *(float4*)(uPack + (size_t)n * 8)     = u0;
      *(float4*)(uPack + (size_t)n * 8 + 4) = u1;
    }
  } else if (b < 1152) {
    // ---- transpose E[k][i] -> ET[i][k] ----
    const int bb = b - 1024;
    const int bk = bb & 31;           // k-tile
    const int bi = bb >> 5;           // i-tile
    const int tx = tid & 31;
    const int ty = tid >> 5;          // 0..15
    #pragma unroll
    for (int r = 0; r < 32; r += 16)
      tile[ty + r][tx] = E[(size_t)(bk * 32 + ty + r) * ND + bi * 32 + tx];
    __syncthreads();
    #pragma unroll
    for (int r = 0; r < 32; r += 16)
      ET[(size_t)(bi * 32 + ty + r) * NK + bk * 32 + tx] = tile[tx][ty + r];
  } else if (b == 1152) {
    // ---- ntot = 0.99*sum(cs) + 0.01*8192 ----
    float s = cs[tid] + cs[tid + 512];
    #pragma unroll
    for (int off = 32; off; off >>= 1) s += __shfl_xor(s, off);
    const int wv = tid >> 6, lane = tid & 63;
    if (lane == 0) red[wv] = s;
    __syncthreads();
    if (tid == 0) {
      float t = 0.f;
      #pragma unroll
      for (int w = 0; w < 8; ++w) t += red[w];
      ntot[0] = fmaf(0.99f, t, 81.92f);
    }
  } else {
    // ---- zero counts+dw ----
    const int idx4 = (b - 1153) * 512 + tid;
    if (idx4 < 33024) {
      float4 zv; zv.x = zv.y = zv.z = zv.w = 0.f;
      *(float4*)(zeroReg + (size_t)idx4 * 4) = zv;
    }
  }
}

// ---------------------------------------------------------------------------
// kDist: stage L(8n) from Lpack into LDS; phase-2 distance+argmin (bitwise
// identical to R3); fused scatter epilogue (counts/dw atomics + index write).
// ---------------------------------------------------------------------------
__global__ __launch_bounds__(256, 2)
void kDist(const float* __restrict__ z, const float* __restrict__ Lp,
           const float* __restrict__ up, const float* __restrict__ ET,
           float* __restrict__ outIdxF, float* __restrict__ counts,
           float* __restrict__ dw)
{
  __shared__ float sL[NB * 1024];
  __shared__ float sU[NB * 8];
  __shared__ float sTv[16];
  __shared__ int   sTi[16];

  const int tid  = threadIdx.x;
  const int wave = tid >> 6;
  const int lane = tid & 63;
  const int base_n = blockIdx.x * NB;

  // stage L: 2048 float4
  #pragma unroll
  for (int it = 0; it < 8; ++it) {
    const int idx4 = it * 256 + tid;
    *(float4*)(sL + (size_t)idx4 * 4) =
        *(const float4*)(Lp + (size_t)base_n * 1024 + (size_t)idx4 * 4);
  }
  if (tid < 64) sU[tid] = up[(size_t)base_n * 8 + tid];
  __syncthreads();

  // -------- 8 wave-tasks (n-pair, khalf), 2 per wave, 2 n each --------
  for (int t = 0; t < 2; ++t) {
    const int task  = wave * 2 + t;
    const int npair = task >> 1;
    const int khalf = task & 1;
    const int n0l = npair * 2, n1l = npair * 2 + 1;
    const float* lb0 = &sL[n0l * 1024];
    const float* lb1 = &sL[n1l * 1024];
    const float* etA = ET + (size_t)khalf * 512 + lane * 4;
    const float* etB = etA + 256;

    float a0A[4][RANK], a0B[4][RANK], a1A[4][RANK], a1B[4][RANK];
    #pragma unroll
    for (int j = 0; j < 4; ++j)
      #pragma unroll
      for (int r = 0; r < RANK; ++r) {
        a0A[j][r] = 0.f; a0B[j][r] = 0.f; a1A[j][r] = 0.f; a1B[j][r] = 0.f;
      }

    #pragma unroll 4
    for (int i = 0; i < ND; ++i) {
      const float4 p0 = *(const float4*)(lb0 + (size_t)i * 8);
      const float4 q0 = *(const float4*)(lb0 + (size_t)i * 8 + 4);
      const float4 p1 = *(const float4*)(lb1 + (size_t)i * 8);
      const float4 q1 = *(const float4*)(lb1 + (size_t)i * 8 + 4);
      const float4 ea = *(const float4*)(etA + (size_t)i * NK);
      const float4 eb = *(const float4*)(etB + (size_t)i * NK);
      #pragma unroll
      for (int j = 0; j < 4; ++j) {
        const float va = ECOMP(ea, j);
        const float vb = ECOMP(eb, j);
        FMA8(a0A[j], p0, q0, va);
        FMA8(a0B[j], p0, q0, vb);
        FMA8(a1A[j], p1, q1, va);
        FMA8(a1B[j], p1, q1, vb);
      }
    }

    float u0[RANK], u1[RANK];
    #pragma unroll
    for (int r = 0; r < RANK; ++r) { u0[r] = sU[n0l * 8 + r]; u1[r] = sU[n1l * 8 + r]; }

    float bv0 = 3.4e38f, bv1 = 3.4e38f;
    int   bi0 = 1 << 30, bi1 = 1 << 30;
    const int kbase = khalf * 512 + lane * 4;
    #pragma unroll
    for (int j = 0; j < 4; ++j) {
      float d0 = 0.f, d1 = 0.f;
      #pragma unroll
      for (int r = 0; r < RANK; ++r) {
        const float t0 = u0[r] - a0A[j][r]; d0 = fmaf(t0, t0, d0);
        const float t1 = u1[r] - a1A[j][r]; d1 = fmaf(t1, t1, d1);
      }
      const int k = kbase + j;
      if (d0 < bv0) { bv0 = d0; bi0 = k; }
      if (d1 < bv1) { bv1 = d1; bi1 = k; }
    }
    #pragma unroll
    for (int j = 0; j < 4; ++j) {
      float d0 = 0.f, d1 = 0.f;
      #pragma unroll
      for (int r = 0; r < RANK; ++r) {
        const float t0 = u0[r] - a0B[j][r]; d0 = fmaf(t0, t0, d0);
        const float t1 = u1[r] - a1B[j][r]; d1 = fmaf(t1, t1, d1);
      }
      const int k = kbase + 256 + j;
      if (d0 < bv0) { bv0 = d0; bi0 = k; }
      if (d1 < bv1) { bv1 = d1; bi1 = k; }
    }
    #pragma unroll
    for (int off = 32; off; off >>= 1) {
      const float ov0 = __shfl_xor(bv0, off);
      const int   oi0 = __shfl_xor(bi0, off);
      if (ov0 < bv0 || (ov0 == bv0 && oi0 < bi0)) { bv0 = ov0; bi0 = oi0; }
      const float ov1 = __shfl_xor(bv1, off);
      const int   oi1 = __shfl_xor(bi1, off);
      if (ov1 < bv1 || (ov1 == bv1 && oi1 < bi1)) { bv1 = ov1; bi1 = oi1; }
    }
    if (lane == 0) {
      sTv[n0l * 2 + khalf] = bv0; sTi[n0l * 2 + khalf] = bi0;
      sTv[n1l * 2 + khalf] = bv1; sTi[n1l * 2 + khalf] = bi1;
    }
  }
  __syncthreads();

  // -------- fused scatter epilogue: wave handles 2 n --------
  for (int t = 0; t < 2; ++t) {
    const int nl = wave * 2 + t;
    const float v0 = sTv[nl * 2], v1 = sTv[nl * 2 + 1];
    const int   j0 = sTi[nl * 2], j1 = sTi[nl * 2 + 1];
    const int   bi = (v1 < v0) ? j1 : j0;   // khalf0 wins ties (smaller k)
    const int n = base_n + nl;
    if (lane == 0) {
      outIdxF[n] = (float)bi;
      atomicAdd(&counts[bi], 1.0f);
    }
    const float z0 = z[(size_t)n * ND + lane];
    const float z1 = z[(size_t)n * ND + lane + 64];
    atomicAdd(&dw[bi * ND + lane],      z0);
    atomicAdd(&dw[bi * ND + lane + 64], z1);
  }
}

// ---------------------------------------------------------------------------
// kFinal: all EMA outputs in one pass
// ---------------------------------------------------------------------------
__global__ __launch_bounds__(256)
void kFinal(const float* __restrict__ cs, const float* __restrict__ ema,
            const float* __restrict__ counts, const float* __restrict__ dw,
            const float* __restrict__ ntot, float* __restrict__ outCs,
            float* __restrict__ outEmb, float* __restrict__ outEma)
{
  const int e = blockIdx.x * 256 + threadIdx.x;   // 0..131071
  const int k = e >> 7;
  const float nt = ntot[0];
  const float v  = cs[k] * 0.99f + 0.01f * counts[k];
  const float sm = (v + 1e-5f) / (nt + 1024.0f * 1e-5f) * nt;
  const float nv = ema[e] * 0.99f + 0.01f * dw[e];
  outEma[e] = nv;
  outEmb[e] = nv / sm;
  if ((e & 127) == 0) outCs[k] = v;
}

extern "C" void kernel_launch(void* const* d_in, const int* in_sizes, int n_in,
                              void* d_out, int out_size, void* d_ws, size_t ws_size,
                              hipStream_t stream)
{
  const float* z  = (const float*)d_in[0];
  const float* G  = (const float*)d_in[1];
  const float* E  = (const float*)d_in[2];
  const float* cs = (const float*)d_in[3];
  const float* ew = (const float*)d_in[4];
  float* out = (float*)d_out;

  char*  ws      = (char*)d_ws;
  float* wLpack  = (float*)(ws + WSB_LPACK);
  float* wUpack  = (float*)(ws + WSB_UPACK);
  float* wET     = (float*)(ws + WSB_ET);
  float* wNtot   = (float*)(ws + WSB_NTOT);
  float* wCounts = (float*)(ws + WSB_COUNTS);
  float* wDw     = (float*)(ws + WSB_DW);

  // 1) factor all n + transpose E + ntot + zero counts/dw (one dispatch)
  kPre<<<1218, 512, 0, stream>>>(z, G, E, cs, wLpack, wUpack, wET, wNtot, wCounts);
  // 2) distances + argmin + fused scatter
  kDist<<<NROWS / NB, 256, 0, stream>>>(z, wLpack, wUpack, wET, out, wCounts, wDw);
  // 3) EMA epilogue (single pass)
  kFinal<<<131072 / 256, 256, 0, stream>>>(cs, ew, wCounts, wDw, wNtot,
                                           out + OFF_CS, out + OFF_EMB, out + OFF_EMA);
}

// Round 5
// 159.790 us; speedup vs baseline: 2.1928x; 1.5170x over previous
//
#include <hip/hip_runtime.h>
#include <cstdint>
#include <cstddef>

#define ND 128
#define NK 1024
#define NROWS 8192
#define RANK 8

#define OFF_EMB 8192
#define OFF_CS  139264
#define OFF_EMA 140288

// workspace byte offsets
#define WSB_LTH 0u                    // Lt_hi  bf16 [8192][8][128]
#define WSB_LTM 16777216u             // Lt_mid bf16
#define WSB_LTL 33554432u             // Lt_lo  bf16
#define WSB_U   50331648u             // u f32 [8192][8]
#define WSB_EH  50593792u             // E_hi  bf16 [1024][128]
#define WSB_EM  50855936u
#define WSB_EL  51118080u
#define WSB_NTOT 51380224u
#define WSB_COUNTS 51380480u          // 1024 f32
#define WSB_DW  51384576u             // 131072 f32

typedef __attribute__((ext_vector_type(8))) short bf16x8;
typedef __attribute__((ext_vector_type(4))) float f32x4;

__device__ __forceinline__ short f2bf(float v) {
  union { float f; unsigned u; } a; a.f = v;
  unsigned r = a.u + 0x7fffu + ((a.u >> 16) & 1u);
  return (short)(r >> 16);
}
__device__ __forceinline__ float bf2f(short s) {
  union { unsigned u; float f; } a; a.u = ((unsigned)(unsigned short)s) << 16;
  return a.f;
}

__device__ __forceinline__ void gl_lds16(const short* gsrc, const short* lds) {
  __builtin_amdgcn_global_load_lds(
      (const __attribute__((address_space(1))) unsigned int*)gsrc,
      (__attribute__((address_space(3))) unsigned int*)lds, 16, 0, 0);
}

// ---------------------------------------------------------------------------
// kPre: b<1024: pivoted Cholesky (1 wave/n), emit Lt splits (bf16 h/m/l,
//       layout [n][r][i]) + u = L^T z (f32).
//       b 1024..1087: E -> Eh/Em/El bf16 splits (row-major [k][i]).
//       b 1088: ntot = 0.99*sum(cs) + 0.01*8192  (sum counts == N always)
//       b 1089..1153: zero counts+dw (33024 float4).
// ---------------------------------------------------------------------------
__global__ __launch_bounds__(512)
void kPre(const float* __restrict__ z, const float* __restrict__ G,
          const float* __restrict__ E, const float* __restrict__ cs,
          short* __restrict__ Lth, short* __restrict__ Ltm, short* __restrict__ Ltl,
          float* __restrict__ uPack,
          short* __restrict__ Eh, short* __restrict__ Em, short* __restrict__ El,
          float* __restrict__ ntot, float* __restrict__ zeroReg)
{
  __shared__ float red[8];
  const int b   = blockIdx.x;
  const int tid = threadIdx.x;

  if (b < 1024) {
    const int wave = tid >> 6, lane = tid & 63;
    const int n = b * 8 + wave;
    const size_t gb = (size_t)n * (ND * ND);
    const int i0 = lane, i1 = lane + 64;
    float d0 = G[gb + (size_t)i0 * ND + i0];
    float d1 = G[gb + (size_t)i1 * ND + i1];
    float L0[RANK], L1[RANK];
    #pragma unroll
    for (int j = 0; j < RANK; ++j) {
      float mv; int p;
      if (d1 > d0) { mv = d1; p = i1; } else { mv = d0; p = i0; }
      #pragma unroll
      for (int off = 32; off; off >>= 1) {
        const float ov = __shfl_xor(mv, off);
        const int   op = __shfl_xor(p, off);
        if (ov > mv || (ov == mv && op < p)) { mv = ov; p = op; }
      }
      const float s = (mv > 1e-12f) ? (1.0f / sqrtf(mv)) : 0.0f;
      float c0 = G[gb + (size_t)p * ND + i0];
      float c1 = G[gb + (size_t)p * ND + i1];
      #pragma unroll
      for (int t = 0; t < j; ++t) {
        const float lsel = (p < 64) ? L0[t] : L1[t];
        const float lpt  = __shfl(lsel, p & 63);
        c0 -= L0[t] * lpt;
        c1 -= L1[t] * lpt;
      }
      const float l0 = c0 * s, l1 = c1 * s;
      L0[j] = l0; L1[j] = l1;
      d0 -= l0 * l0;
      d1 -= l1 * l1;
    }
    // Lt splits: [n][r][i]
    #pragma unroll
    for (int r = 0; r < RANK; ++r) {
      const size_t o0 = ((size_t)n * 8 + r) * 128 + i0;
      const size_t o1 = ((size_t)n * 8 + r) * 128 + i1;
      float v = L0[r];
      short h = f2bf(v); float fh = bf2f(h);
      short m = f2bf(v - fh); float fm = bf2f(m);
      short l = f2bf(v - fh - fm);
      Lth[o0] = h; Ltm[o0] = m; Ltl[o0] = l;
      v = L1[r];
      h = f2bf(v); fh = bf2f(h);
      m = f2bf(v - fh); fm = bf2f(m);
      l = f2bf(v - fh - fm);
      Lth[o1] = h; Ltm[o1] = m; Ltl[o1] = l;
    }
    // u = L^T z
    const float z0 = z[(size_t)n * ND + i0];
    const float z1 = z[(size_t)n * ND + i1];
    float pu[RANK];
    #pragma unroll
    for (int r = 0; r < RANK; ++r) pu[r] = L0[r] * z0 + L1[r] * z1;
    #pragma unroll
    for (int off = 32; off; off >>= 1) {
      #pragma unroll
      for (int r = 0; r < RANK; ++r) pu[r] += __shfl_xor(pu[r], off);
    }
    if (lane == 0) {
      #pragma unroll
      for (int r = 0; r < RANK; ++r) uPack[(size_t)n * 8 + r] = pu[r];
    }
  } else if (b < 1088) {
    // E splits
    const int e4 = (b - 1024) * 2048 + tid * 4;
    const float4 v = *(const float4*)(E + e4);
    short h[4], m[4], l[4];
    const float vf[4] = {v.x, v.y, v.z, v.w};
    #pragma unroll
    for (int c = 0; c < 4; ++c) {
      h[c] = f2bf(vf[c]); float fh = bf2f(h[c]);
      m[c] = f2bf(vf[c] - fh); float fm = bf2f(m[c]);
      l[c] = f2bf(vf[c] - fh - fm);
    }
    *(short4*)(Eh + e4) = make_short4(h[0], h[1], h[2], h[3]);
    *(short4*)(Em + e4) = make_short4(m[0], m[1], m[2], m[3]);
    *(short4*)(El + e4) = make_short4(l[0], l[1], l[2], l[3]);
  } else if (b == 1088) {
    float s = cs[tid] + cs[tid + 512];
    #pragma unroll
    for (int off = 32; off; off >>= 1) s += __shfl_xor(s, off);
    const int wv = tid >> 6, lane = tid & 63;
    if (lane == 0) red[wv] = s;
    __syncthreads();
    if (tid == 0) {
      float t = 0.f;
      #pragma unroll
      for (int w = 0; w < 8; ++w) t += red[w];
      ntot[0] = fmaf(0.99f, t, 81.92f);
    }
  } else {
    const int idx4 = (b - 1089) * 512 + tid;
    if (idx4 < 33024) {
      float4 zv; zv.x = zv.y = zv.z = zv.w = 0.f;
      *(float4*)(zeroReg + (size_t)idx4 * 4) = zv;
    }
  }
}

// ---------------------------------------------------------------------------
// kDist: 8 n per block, 4 waves. Wave w: k-half (w&1), n-pairs {2*(w>>1), +1}.
// A = L^T (hoisted regs, 3 splits x 4 ksteps x 2 npairs), B = E tile (LDS,
// XOR-swizzled, double-buffered via global_load_lds with pre-swizzled src).
// 6-term bf16 split MFMA -> V; dist = sum_r (u_r - V_r)^2; argmin + scatter.
// ---------------------------------------------------------------------------
__global__ __launch_bounds__(256, 2)
void kDist(const float* __restrict__ z,
           const short* __restrict__ Lth, const short* __restrict__ Ltm,
           const short* __restrict__ Ltl, const float* __restrict__ uPack,
           const short* __restrict__ Eh, const short* __restrict__ Em,
           const short* __restrict__ El,
           float* __restrict__ outIdxF, float* __restrict__ counts,
           float* __restrict__ dw)
{
  __shared__ __align__(16) short sEs[24576];   // 2 bufs x [2 kh][3 split][4096B]
  __shared__ float sU[64];
  __shared__ float sV[2][8];
  __shared__ int   sI[2][8];
  __shared__ int   sBI[8];

  const int tid  = threadIdx.x;
  const int wave = tid >> 6;
  const int lane = tid & 63;
  const int g    = wave >> 1;      // n-pair-group: owns npairs {2g, 2g+1}
  const int kh   = wave & 1;       // k-half
  const int base_n = blockIdx.x * 8;

  if (tid < 64) sU[tid] = uPack[(size_t)base_n * 8 + tid];

  // ---- hoist A-frags (L^T) to registers: [pp][ks], 3 splits ----
  bf16x8 Ah[2][4], Am[2][4], Al[2][4];
  #pragma unroll
  for (int pp = 0; pp < 2; ++pp) {
    const int nloc = (g * 2 + pp) * 2 + ((lane & 15) >> 3);
    const size_t rowb = ((size_t)(base_n + nloc) * 8 + (lane & 7)) * 128 + ((lane >> 4) * 8);
    #pragma unroll
    for (int ks = 0; ks < 4; ++ks) {
      Ah[pp][ks] = *(const bf16x8*)(Lth + rowb + ks * 32);
      Am[pp][ks] = *(const bf16x8*)(Ltm + rowb + ks * 32);
      Al[pp][ks] = *(const bf16x8*)(Ltl + rowb + ks * 32);
    }
  }

  // ---- staging helper: load tile pair (it, 32+it) into buf d ----
  const char* sBase = (const char*)sEs;
  auto STAGE = [&](int it, int d) {
    #pragma unroll
    for (int c = 0; c < 6; ++c) {
      const int ch  = wave * 6 + c;          // 0..23, wave-uniform
      const int blk = ch >> 2;               // 0..5 = khB*3+split
      const int khB = (blk >= 3) ? 1 : 0;
      const int split = blk - khB * 3;
      const int x = ((ch & 3) << 10) + (lane << 4);     // logical byte in 4KB tile
      const int P = x ^ (((x >> 8) & 7) << 4);          // pre-swizzled source
      const short* gbp = (split == 0) ? Eh : (split == 1) ? Em : El;
      const short* gs = gbp + (size_t)(khB ? (32 + it) : it) * 2048 + (P >> 1);
      const short* ld = (const short*)(sBase + d * 24576 + ch * 1024);
      gl_lds16(gs, ld);
    }
  };

  STAGE(0, 0);
  __syncthreads();

  // per-lane u values for the 4 C rows, both npairs
  float uv0[4], uv1[4];
  #pragma unroll
  for (int reg = 0; reg < 4; ++reg) {
    const int nr = (lane >> 4) * 4 + reg;
    uv0[reg] = sU[((g * 2 + 0) * 2 + (nr >> 3)) * 8 + (nr & 7)];
    uv1[reg] = sU[((g * 2 + 1) * 2 + (nr >> 3)) * 8 + (nr & 7)];
  }

  const int x0 = ((lane & 15) << 8) + ((lane >> 4) << 4);
  const int xm = (lane & 7) << 4;

  float bv0 = 3.4e38f, bv1 = 3.4e38f;
  int   bi0 = 1 << 30, bi1 = 1 << 30;

  for (int it = 0; it < 32; ++it) {
    if (it + 1 < 32) STAGE(it + 1, (it + 1) & 1);

    const int bufoff = (it & 1) * 24576 + kh * 12288;
    f32x4 C0 = {0.f, 0.f, 0.f, 0.f};
    f32x4 C1 = {0.f, 0.f, 0.f, 0.f};
    #pragma unroll
    for (int ks = 0; ks < 4; ++ks) {
      const int sx = (x0 + (ks << 6)) ^ xm;
      const char* p = sBase + bufoff + sx;
      const bf16x8 Bh = *(const bf16x8*)(p);
      const bf16x8 Bm = *(const bf16x8*)(p + 4096);
      const bf16x8 Bl = *(const bf16x8*)(p + 8192);
      C0 = __builtin_amdgcn_mfma_f32_16x16x32_bf16(Ah[0][ks], Bh, C0, 0, 0, 0);
      C0 = __builtin_amdgcn_mfma_f32_16x16x32_bf16(Ah[0][ks], Bm, C0, 0, 0, 0);
      C0 = __builtin_amdgcn_mfma_f32_16x16x32_bf16(Am[0][ks], Bh, C0, 0, 0, 0);
      C0 = __builtin_amdgcn_mfma_f32_16x16x32_bf16(Am[0][ks], Bm, C0, 0, 0, 0);
      C0 = __builtin_amdgcn_mfma_f32_16x16x32_bf16(Ah[0][ks], Bl, C0, 0, 0, 0);
      C0 = __builtin_amdgcn_mfma_f32_16x16x32_bf16(Al[0][ks], Bh, C0, 0, 0, 0);
      C1 = __builtin_amdgcn_mfma_f32_16x16x32_bf16(Ah[1][ks], Bh, C1, 0, 0, 0);
      C1 = __builtin_amdgcn_mfma_f32_16x16x32_bf16(Ah[1][ks], Bm, C1, 0, 0, 0);
      C1 = __builtin_amdgcn_mfma_f32_16x16x32_bf16(Am[1][ks], Bh, C1, 0, 0, 0);
      C1 = __builtin_amdgcn_mfma_f32_16x16x32_bf16(Am[1][ks], Bm, C1, 0, 0, 0);
      C1 = __builtin_amdgcn_mfma_f32_16x16x32_bf16(Ah[1][ks], Bl, C1, 0, 0, 0);
      C1 = __builtin_amdgcn_mfma_f32_16x16x32_bf16(Al[1][ks], Bh, C1, 0, 0, 0);
    }

    // dist epilogue: in-register r-sum over 4 regs + one xor16 (q-pair merge)
    float s0 = 0.f, s1 = 0.f;
    #pragma unroll
    for (int reg = 0; reg < 4; ++reg) {
      const float t0 = uv0[reg] - C0[reg]; s0 = fmaf(t0, t0, s0);
      const float t1 = uv1[reg] - C1[reg]; s1 = fmaf(t1, t1, s1);
    }
    s0 += __shfl_xor(s0, 16);
    s1 += __shfl_xor(s1, 16);
    const int k = ((kh << 5) + it) * 16 + (lane & 15);
    if (s0 < bv0 || (s0 == bv0 && k < bi0)) { bv0 = s0; bi0 = k; }
    if (s1 < bv1 || (s1 == bv1 && k < bi1)) { bv1 = s1; bi1 = k; }

    __syncthreads();
  }

  // reduce over 16 k-columns (tie-break smaller k)
  #pragma unroll
  for (int off = 1; off < 16; off <<= 1) {
    const float o0 = __shfl_xor(bv0, off); const int j0 = __shfl_xor(bi0, off);
    if (o0 < bv0 || (o0 == bv0 && j0 < bi0)) { bv0 = o0; bi0 = j0; }
    const float o1 = __shfl_xor(bv1, off); const int j1 = __shfl_xor(bi1, off);
    if (o1 < bv1 || (o1 == bv1 && j1 < bi1)) { bv1 = o1; bi1 = j1; }
  }
  // lane 0: n-even results; lane 32: n-odd
  if (lane == 0) {
    sV[kh][(g * 2 + 0) * 2 + 0] = bv0; sI[kh][(g * 2 + 0) * 2 + 0] = bi0;
    sV[kh][(g * 2 + 1) * 2 + 0] = bv1; sI[kh][(g * 2 + 1) * 2 + 0] = bi1;
  }
  if (lane == 32) {
    sV[kh][(g * 2 + 0) * 2 + 1] = bv0; sI[kh][(g * 2 + 0) * 2 + 1] = bi0;
    sV[kh][(g * 2 + 1) * 2 + 1] = bv1; sI[kh][(g * 2 + 1) * 2 + 1] = bi1;
  }
  __syncthreads();

  if (tid < 8) {
    const float v0 = sV[0][tid], v1 = sV[1][tid];
    const int   j0 = sI[0][tid], j1 = sI[1][tid];
    const int   bi = (v1 < v0) ? j1 : j0;   // khalf0 k's all smaller: ties -> khalf0
    sBI[tid] = bi;
    outIdxF[base_n + tid] = (float)bi;
    atomicAdd(&counts[bi], 1.0f);
  }
  __syncthreads();

  // dw scatter: 32 threads x 4 dims per n
  const int nl = tid >> 5;
  const int d0 = (tid & 31) * 4;
  const int bk = sBI[nl];
  const float4 zv = *(const float4*)(z + (size_t)(base_n + nl) * ND + d0);
  atomicAdd(&dw[bk * ND + d0 + 0], zv.x);
  atomicAdd(&dw[bk * ND + d0 + 1], zv.y);
  atomicAdd(&dw[bk * ND + d0 + 2], zv.z);
  atomicAdd(&dw[bk * ND + d0 + 3], zv.w);
}

// ---------------------------------------------------------------------------
__global__ __launch_bounds__(256)
void kFinal(const float* __restrict__ cs, const float* __restrict__ ema,
            const float* __restrict__ counts, const float* __restrict__ dw,
            const float* __restrict__ ntot, float* __restrict__ outCs,
            float* __restrict__ outEmb, float* __restrict__ outEma)
{
  const int e = blockIdx.x * 256 + threadIdx.x;
  const int k = e >> 7;
  const float nt = ntot[0];
  const float v  = cs[k] * 0.99f + 0.01f * counts[k];
  const float sm = (v + 1e-5f) / (nt + 1024.0f * 1e-5f) * nt;
  const float nv = ema[e] * 0.99f + 0.01f * dw[e];
  outEma[e] = nv;
  outEmb[e] = nv / sm;
  if ((e & 127) == 0) outCs[k] = v;
}

extern "C" void kernel_launch(void* const* d_in, const int* in_sizes, int n_in,
                              void* d_out, int out_size, void* d_ws, size_t ws_size,
                              hipStream_t stream)
{
  const float* z  = (const float*)d_in[0];
  const float* G  = (const float*)d_in[1];
  const float* E  = (const float*)d_in[2];
  const float* cs = (const float*)d_in[3];
  const float* ew = (const float*)d_in[4];
  float* out = (float*)d_out;

  char* ws = (char*)d_ws;
  short* wLth = (short*)(ws + WSB_LTH);
  short* wLtm = (short*)(ws + WSB_LTM);
  short* wLtl = (short*)(ws + WSB_LTL);
  float* wU   = (float*)(ws + WSB_U);
  short* wEh  = (short*)(ws + WSB_EH);
  short* wEm  = (short*)(ws + WSB_EM);
  short* wEl  = (short*)(ws + WSB_EL);
  float* wNtot   = (float*)(ws + WSB_NTOT);
  float* wCounts = (float*)(ws + WSB_COUNTS);
  float* wDw     = (float*)(ws + WSB_DW);

  kPre<<<1154, 512, 0, stream>>>(z, G, E, cs, wLth, wLtm, wLtl, wU,
                                 wEh, wEm, wEl, wNtot, wCounts);
  kDist<<<1024, 256, 0, stream>>>(z, wLth, wLtm, wLtl, wU, wEh, wEm, wEl,
                                  out, wCounts, wDw);
  kFinal<<<512, 256, 0, stream>>>(cs, ew, wCounts, wDw, wNtot,
                                  out + OFF_CS, out + OFF_EMB, out + OFF_EMA);
}

// Round 6
// 105.443 us; speedup vs baseline: 3.3231x; 1.5154x over previous
//
#include <hip/hip_runtime.h>
#include <cstdint>
#include <cstddef>

#define ND 128
#define NK 1024
#define NROWS 8192
#define RANK 8

#define OFF_EMB 8192
#define OFF_CS  139264
#define OFF_EMA 140288

// workspace byte offsets
#define WSB_LTH 0u                    // Lt_hi  bf16 [8192][8][128]
#define WSB_LTM 16777216u             // Lt_mid bf16
#define WSB_U   33554432u             // u f32 [8192][8]
#define WSB_EH  33816576u             // E_hi  bf16 [1024][128]
#define WSB_EM  34078720u             // E_mid bf16
#define WSB_NTOT 34340864u
#define WSB_COUNTS 34341120u          // 1024 f32
#define WSB_DW  34345216u             // 131072 f32

typedef __attribute__((ext_vector_type(8))) short bf16x8;
typedef __attribute__((ext_vector_type(4))) float f32x4;

__device__ __forceinline__ short f2bf(float v) {
  union { float f; unsigned u; } a; a.f = v;
  unsigned r = a.u + 0x7fffu + ((a.u >> 16) & 1u);
  return (short)(r >> 16);
}
__device__ __forceinline__ float bf2f(short s) {
  union { unsigned u; float f; } a; a.u = ((unsigned)(unsigned short)s) << 16;
  return a.f;
}

__device__ __forceinline__ void gl_lds16(const short* gsrc, const short* lds) {
  __builtin_amdgcn_global_load_lds(
      (const __attribute__((address_space(1))) unsigned int*)gsrc,
      (__attribute__((address_space(3))) unsigned int*)lds, 16, 0, 0);
}

// ---------------------------------------------------------------------------
// kPre: b<1024: pivoted Cholesky (1 wave/n), emit Lt splits (bf16 h/m,
//       layout [n][r][i]) + u = L^T z (f32).
//       b 1024..1087: E -> Eh/Em bf16 splits (row-major [k][i]).
//       b 1088: ntot = 0.99*sum(cs) + 0.01*8192  (sum counts == N always)
//       b 1089..1153: zero counts+dw (33024 float4).
// ---------------------------------------------------------------------------
__global__ __launch_bounds__(512)
void kPre(const float* __restrict__ z, const float* __restrict__ G,
          const float* __restrict__ E, const float* __restrict__ cs,
          short* __restrict__ Lth, short* __restrict__ Ltm,
          float* __restrict__ uPack,
          short* __restrict__ Eh, short* __restrict__ Em,
          float* __restrict__ ntot, float* __restrict__ zeroReg)
{
  __shared__ float red[8];
  const int b   = blockIdx.x;
  const int tid = threadIdx.x;

  if (b < 1024) {
    const int wave = tid >> 6, lane = tid & 63;
    const int n = b * 8 + wave;
    const size_t gb = (size_t)n * (ND * ND);
    const int i0 = lane, i1 = lane + 64;
    float d0 = G[gb + (size_t)i0 * ND + i0];
    float d1 = G[gb + (size_t)i1 * ND + i1];
    float L0[RANK], L1[RANK];
    #pragma unroll
    for (int j = 0; j < RANK; ++j) {
      float mv; int p;
      if (d1 > d0) { mv = d1; p = i1; } else { mv = d0; p = i0; }
      #pragma unroll
      for (int off = 32; off; off >>= 1) {
        const float ov = __shfl_xor(mv, off);
        const int   op = __shfl_xor(p, off);
        if (ov > mv || (ov == mv && op < p)) { mv = ov; p = op; }
      }
      const float s = (mv > 1e-12f) ? (1.0f / sqrtf(mv)) : 0.0f;
      float c0 = G[gb + (size_t)p * ND + i0];
      float c1 = G[gb + (size_t)p * ND + i1];
      #pragma unroll
      for (int t = 0; t < j; ++t) {
        const float lsel = (p < 64) ? L0[t] : L1[t];
        const float lpt  = __shfl(lsel, p & 63);
        c0 -= L0[t] * lpt;
        c1 -= L1[t] * lpt;
      }
      const float l0 = c0 * s, l1 = c1 * s;
      L0[j] = l0; L1[j] = l1;
      d0 -= l0 * l0;
      d1 -= l1 * l1;
    }
    // Lt splits: [n][r][i]
    #pragma unroll
    for (int r = 0; r < RANK; ++r) {
      const size_t o0 = ((size_t)n * 8 + r) * 128 + i0;
      const size_t o1 = ((size_t)n * 8 + r) * 128 + i1;
      float v = L0[r];
      short h = f2bf(v);
      short m = f2bf(v - bf2f(h));
      Lth[o0] = h; Ltm[o0] = m;
      v = L1[r];
      h = f2bf(v);
      m = f2bf(v - bf2f(h));
      Lth[o1] = h; Ltm[o1] = m;
    }
    // u = L^T z
    const float z0 = z[(size_t)n * ND + i0];
    const float z1 = z[(size_t)n * ND + i1];
    float pu[RANK];
    #pragma unroll
    for (int r = 0; r < RANK; ++r) pu[r] = L0[r] * z0 + L1[r] * z1;
    #pragma unroll
    for (int off = 32; off; off >>= 1) {
      #pragma unroll
      for (int r = 0; r < RANK; ++r) pu[r] += __shfl_xor(pu[r], off);
    }
    if (lane == 0) {
      #pragma unroll
      for (int r = 0; r < RANK; ++r) uPack[(size_t)n * 8 + r] = pu[r];
    }
  } else if (b < 1088) {
    // E splits
    const int e4 = (b - 1024) * 2048 + tid * 4;
    const float4 v = *(const float4*)(E + e4);
    short h[4], m[4];
    const float vf[4] = {v.x, v.y, v.z, v.w};
    #pragma unroll
    for (int c = 0; c < 4; ++c) {
      h[c] = f2bf(vf[c]);
      m[c] = f2bf(vf[c] - bf2f(h[c]));
    }
    *(short4*)(Eh + e4) = make_short4(h[0], h[1], h[2], h[3]);
    *(short4*)(Em + e4) = make_short4(m[0], m[1], m[2], m[3]);
  } else if (b == 1088) {
    float s = cs[tid] + cs[tid + 512];
    #pragma unroll
    for (int off = 32; off; off >>= 1) s += __shfl_xor(s, off);
    const int wv = tid >> 6, lane = tid & 63;
    if (lane == 0) red[wv] = s;
    __syncthreads();
    if (tid == 0) {
      float t = 0.f;
      #pragma unroll
      for (int w = 0; w < 8; ++w) t += red[w];
      ntot[0] = fmaf(0.99f, t, 81.92f);
    }
  } else {
    const int idx4 = (b - 1089) * 512 + tid;
    if (idx4 < 33024) {
      float4 zv; zv.x = zv.y = zv.z = zv.w = 0.f;
      *(float4*)(zeroReg + (size_t)idx4 * 4) = zv;
    }
  }
}

// ---------------------------------------------------------------------------
// kDist: 8 n per block, 4 waves. Wave w: k-half (w&1), n-pairs {2*(w>>1), +1}.
// A = L^T (hoisted regs, 2 splits x 4 ksteps x 2 npairs), B = E tile (LDS,
// XOR-swizzled, double-buffered via global_load_lds with pre-swizzled src).
// 3-term bf16 split MFMA (hh+hm+mh) -> V; dist = sum_r (u_r - V_r)^2.
// ---------------------------------------------------------------------------
__global__ __launch_bounds__(256, 3)
void kDist(const float* __restrict__ z,
           const short* __restrict__ Lth, const short* __restrict__ Ltm,
           const float* __restrict__ uPack,
           const short* __restrict__ Eh, const short* __restrict__ Em,
           float* __restrict__ outIdxF, float* __restrict__ counts,
           float* __restrict__ dw)
{
  __shared__ __align__(16) short sEs[16384];   // 2 bufs x [2 kh][2 split][4096B]
  __shared__ float sU[64];
  __shared__ float sV[2][8];
  __shared__ int   sI[2][8];
  __shared__ int   sBI[8];

  const int tid  = threadIdx.x;
  const int wave = tid >> 6;
  const int lane = tid & 63;
  const int g    = wave >> 1;      // n-pair-group: owns npairs {2g, 2g+1}
  const int kh   = wave & 1;       // k-half
  const int base_n = blockIdx.x * 8;

  if (tid < 64) sU[tid] = uPack[(size_t)base_n * 8 + tid];

  // ---- hoist A-frags (L^T) to registers: [pp][ks], 2 splits ----
  bf16x8 Ah[2][4], Am[2][4];
  #pragma unroll
  for (int pp = 0; pp < 2; ++pp) {
    const int nloc = (g * 2 + pp) * 2 + ((lane & 15) >> 3);
    const size_t rowb = ((size_t)(base_n + nloc) * 8 + (lane & 7)) * 128 + ((lane >> 4) * 8);
    #pragma unroll
    for (int ks = 0; ks < 4; ++ks) {
      Ah[pp][ks] = *(const bf16x8*)(Lth + rowb + ks * 32);
      Am[pp][ks] = *(const bf16x8*)(Ltm + rowb + ks * 32);
    }
  }

  // ---- staging: load tile pair (it, 32+it) into buf d; 4 channels/wave ----
  const char* sBase = (const char*)sEs;
  auto STAGE = [&](int it, int d) {
    #pragma unroll
    for (int c = 0; c < 4; ++c) {
      const int ch    = wave * 4 + c;        // 0..15, wave-uniform
      const int khB   = ch >> 3;
      const int split = (ch >> 2) & 1;
      const int x = ((ch & 3) << 10) + (lane << 4);     // logical byte in 4KB tile
      const int P = x ^ (((x >> 8) & 7) << 4);          // pre-swizzled source
      const short* gbp = split ? Em : Eh;
      const short* gs = gbp + (size_t)(khB ? (32 + it) : it) * 2048 + (P >> 1);
      const short* ld = (const short*)(sBase + d * 16384 + ch * 1024);
      gl_lds16(gs, ld);
    }
  };

  STAGE(0, 0);
  __syncthreads();

  // per-lane u values for the 4 C rows, both npairs
  float uv0[4], uv1[4];
  #pragma unroll
  for (int reg = 0; reg < 4; ++reg) {
    const int nr = (lane >> 4) * 4 + reg;
    uv0[reg] = sU[((g * 2 + 0) * 2 + (nr >> 3)) * 8 + (nr & 7)];
    uv1[reg] = sU[((g * 2 + 1) * 2 + (nr >> 3)) * 8 + (nr & 7)];
  }

  const int x0 = ((lane & 15) << 8) + ((lane >> 4) << 4);
  const int xm = (lane & 7) << 4;

  float bv0 = 3.4e38f, bv1 = 3.4e38f;
  int   bi0 = 1 << 30, bi1 = 1 << 30;

  for (int it = 0; it < 32; ++it) {
    if (it + 1 < 32) STAGE(it + 1, (it + 1) & 1);

    const int bufoff = (it & 1) * 16384 + kh * 8192;
    f32x4 C0 = {0.f, 0.f, 0.f, 0.f};
    f32x4 C1 = {0.f, 0.f, 0.f, 0.f};
    #pragma unroll
    for (int ks = 0; ks < 4; ++ks) {
      const int sx = (x0 + (ks << 6)) ^ xm;
      const char* p = sBase + bufoff + sx;
      const bf16x8 Bh = *(const bf16x8*)(p);
      const bf16x8 Bm = *(const bf16x8*)(p + 4096);
      C0 = __builtin_amdgcn_mfma_f32_16x16x32_bf16(Ah[0][ks], Bh, C0, 0, 0, 0);
      C0 = __builtin_amdgcn_mfma_f32_16x16x32_bf16(Ah[0][ks], Bm, C0, 0, 0, 0);
      C0 = __builtin_amdgcn_mfma_f32_16x16x32_bf16(Am[0][ks], Bh, C0, 0, 0, 0);
      C1 = __builtin_amdgcn_mfma_f32_16x16x32_bf16(Ah[1][ks], Bh, C1, 0, 0, 0);
      C1 = __builtin_amdgcn_mfma_f32_16x16x32_bf16(Ah[1][ks], Bm, C1, 0, 0, 0);
      C1 = __builtin_amdgcn_mfma_f32_16x16x32_bf16(Am[1][ks], Bh, C1, 0, 0, 0);
    }

    // dist epilogue: in-register r-sum over 4 regs + one xor16 (q-pair merge)
    float s0 = 0.f, s1 = 0.f;
    #pragma unroll
    for (int reg = 0; reg < 4; ++reg) {
      const float t0 = uv0[reg] - C0[reg]; s0 = fmaf(t0, t0, s0);
      const float t1 = uv1[reg] - C1[reg]; s1 = fmaf(t1, t1, s1);
    }
    s0 += __shfl_xor(s0, 16);
    s1 += __shfl_xor(s1, 16);
    const int k = ((kh << 5) + it) * 16 + (lane & 15);
    if (s0 < bv0 || (s0 == bv0 && k < bi0)) { bv0 = s0; bi0 = k; }
    if (s1 < bv1 || (s1 == bv1 && k < bi1)) { bv1 = s1; bi1 = k; }

    __syncthreads();
  }

  // reduce over 16 k-columns (tie-break smaller k)
  #pragma unroll
  for (int off = 1; off < 16; off <<= 1) {
    const float o0 = __shfl_xor(bv0, off); const int j0 = __shfl_xor(bi0, off);
    if (o0 < bv0 || (o0 == bv0 && j0 < bi0)) { bv0 = o0; bi0 = j0; }
    const float o1 = __shfl_xor(bv1, off); const int j1 = __shfl_xor(bi1, off);
    if (o1 < bv1 || (o1 == bv1 && j1 < bi1)) { bv1 = o1; bi1 = j1; }
  }
  // lane 0: n-even results; lane 32: n-odd
  if (lane == 0) {
    sV[kh][(g * 2 + 0) * 2 + 0] = bv0; sI[kh][(g * 2 + 0) * 2 + 0] = bi0;
    sV[kh][(g * 2 + 1) * 2 + 0] = bv1; sI[kh][(g * 2 + 1) * 2 + 0] = bi1;
  }
  if (lane == 32) {
    sV[kh][(g * 2 + 0) * 2 + 1] = bv0; sI[kh][(g * 2 + 0) * 2 + 1] = bi0;
    sV[kh][(g * 2 + 1) * 2 + 1] = bv1; sI[kh][(g * 2 + 1) * 2 + 1] = bi1;
  }
  __syncthreads();

  if (tid < 8) {
    const float v0 = sV[0][tid], v1 = sV[1][tid];
    const int   j0 = sI[0][tid], j1 = sI[1][tid];
    const int   bi = (v1 < v0) ? j1 : j0;   // khalf0 k's all smaller: ties -> khalf0
    sBI[tid] = bi;
    outIdxF[base_n + tid] = (float)bi;
    atomicAdd(&counts[bi], 1.0f);
  }
  __syncthreads();

  // dw scatter: 32 threads x 4 dims per n
  const int nl = tid >> 5;
  const int d0 = (tid & 31) * 4;
  const int bk = sBI[nl];
  const float4 zv = *(const float4*)(z + (size_t)(base_n + nl) * ND + d0);
  atomicAdd(&dw[bk * ND + d0 + 0], zv.x);
  atomicAdd(&dw[bk * ND + d0 + 1], zv.y);
  atomicAdd(&dw[bk * ND + d0 + 2], zv.z);
  atomicAdd(&dw[bk * ND + d0 + 3], zv.w);
}

// ---------------------------------------------------------------------------
__global__ __launch_bounds__(256)
void kFinal(const float* __restrict__ cs, const float* __restrict__ ema,
            const float* __restrict__ counts, const float* __restrict__ dw,
            const float* __restrict__ ntot, float* __restrict__ outCs,
            float* __restrict__ outEmb, float* __restrict__ outEma)
{
  const int e = blockIdx.x * 256 + threadIdx.x;
  const int k = e >> 7;
  const float nt = ntot[0];
  const float v  = cs[k] * 0.99f + 0.01f * counts[k];
  const float sm = (v + 1e-5f) / (nt + 1024.0f * 1e-5f) * nt;
  const float nv = ema[e] * 0.99f + 0.01f * dw[e];
  outEma[e] = nv;
  outEmb[e] = nv / sm;
  if ((e & 127) == 0) outCs[k] = v;
}

extern "C" void kernel_launch(void* const* d_in, const int* in_sizes, int n_in,
                              void* d_out, int out_size, void* d_ws, size_t ws_size,
                              hipStream_t stream)
{
  const float* z  = (const float*)d_in[0];
  const float* G  = (const float*)d_in[1];
  const float* E  = (const float*)d_in[2];
  const float* cs = (const float*)d_in[3];
  const float* ew = (const float*)d_in[4];
  float* out = (float*)d_out;

  char* ws = (char*)d_ws;
  short* wLth = (short*)(ws + WSB_LTH);
  short* wLtm = (short*)(ws + WSB_LTM);
  float* wU   = (float*)(ws + WSB_U);
  short* wEh  = (short*)(ws + WSB_EH);
  short* wEm  = (short*)(ws + WSB_EM);
  float* wNtot   = (float*)(ws + WSB_NTOT);
  float* wCounts = (float*)(ws + WSB_COUNTS);
  float* wDw     = (float*)(ws + WSB_DW);

  kPre<<<1154, 512, 0, stream>>>(z, G, E, cs, wLth, wLtm, wU,
                                 wEh, wEm, wNtot, wCounts);
  kDist<<<1024, 256, 0, stream>>>(z, wLth, wLtm, wU, wEh, wEm,
                                  out, wCounts, wDw);
  kFinal<<<512, 256, 0, stream>>>(cs, ew, wCounts, wDw, wNtot,
                                  out + OFF_CS, out + OFF_EMB, out + OFF_EMA);
}